// Round 2
// baseline (718.458 us; speedup 1.0000x reference)
//
#include <hip/hip_runtime.h>

#define HIDDEN 4096
#define INTER  11008
#define MTOK   128          // B*S = 8*16
#define NMERG  (2*INTER)    // 22016
#define KS1    8            // stage-1 K-split
#define KS2    16           // stage-2 K-split

typedef short  short8  __attribute__((ext_vector_type(8)));
typedef float  f32x16  __attribute__((ext_vector_type(16)));

// round-to-nearest-even fp32 -> bf16 bits
static __device__ __forceinline__ unsigned short f2bf_rne(float f) {
    unsigned u = __builtin_bit_cast(unsigned, f);
    u += 0x7FFFu + ((u >> 16) & 1u);
    return (unsigned short)(u >> 16);
}
static __device__ __forceinline__ float bf2f(unsigned short b) {
    unsigned u = (unsigned)b << 16;
    return __builtin_bit_cast(float, u);
}
// pack two fp32 into bf16x2 by truncation (exact for integer-valued weights)
static __device__ __forceinline__ int pk2(float lo, float hi) {
    return (int)__builtin_amdgcn_perm(__builtin_bit_cast(unsigned, hi),
                                      __builtin_bit_cast(unsigned, lo),
                                      0x07060302u);
}

// ---------------- x fp32 -> bf16 ----------------
__global__ void cvt_x_k(const float* __restrict__ x, unsigned short* __restrict__ xb) {
    int i = (blockIdx.x * 256 + threadIdx.x) * 4;
    float4 v = *(const float4*)(x + i);
    ushort4 o;
    o.x = f2bf_rne(v.x); o.y = f2bf_rne(v.y); o.z = f2bf_rne(v.z); o.w = f2bf_rne(v.w);
    *(ushort4*)(xb + i) = o;
}

// ---------------- fused dequant GEMM partial ----------------
// part[ks][m][n] = sum_{k in chunk ks} A[m][k] * B[n][k]
// A: bf16 [MTOK][K]; B rows fp32 (integer-valued): n<nhalf -> B0 row n else B1 row n-nhalf.
// block = 128 thr (2 waves); wave: 32 n x (MFRAG*32) m. blockIdx.x = ntile*(msplit)+mtile
// (mtile fastest so same-weight blocks are dispatched adjacently -> L2/L3 absorbs re-read).
template<int MFRAG, int MSPLIT_BITS, bool OBF16>
__global__ __launch_bounds__(128) void gemm_part_k(
    const unsigned short* __restrict__ Abf,
    const float* __restrict__ B0, const float* __restrict__ B1, int nhalf,
    void* __restrict__ part, int K, int N, int kchunk)
{
    const int lane  = threadIdx.x & 63;
    const int wave  = threadIdx.x >> 6;
    const int mtile = blockIdx.x & ((1 << MSPLIT_BITS) - 1);
    const int ntile = blockIdx.x >> MSPLIT_BITS;
    const int n     = ntile * 64 + wave * 32 + (lane & 31);
    const int m0    = mtile * (MFRAG * 32);
    const int ks    = blockIdx.y;
    const int kq    = (lane >> 5) * 8;     // k sub-offset within 16-step

    const float* Brow = (n < nhalf) ? (B0 + (size_t)n * K)
                                    : (B1 + (size_t)(n - nhalf) * K);
    const int kbeg = ks * kchunk;
    const float* bp = Brow + kbeg + kq;
    const unsigned short* ap = Abf + (size_t)(m0 + (lane & 31)) * K + kbeg + kq;
    const size_t mstride = (size_t)32 * K;

    f32x16 acc[MFRAG];
#pragma unroll
    for (int t = 0; t < MFRAG; ++t)
#pragma unroll
        for (int r = 0; r < 16; ++r) acc[t][r] = 0.f;

#pragma unroll 2
    for (int k = 0; k < kchunk; k += 16) {
        float4 b0 = *(const float4*)(bp);
        float4 b1 = *(const float4*)(bp + 4);
        int4 bi;
        bi.x = pk2(b0.x, b0.y); bi.y = pk2(b0.z, b0.w);
        bi.z = pk2(b1.x, b1.y); bi.w = pk2(b1.z, b1.w);
        short8 bf = __builtin_bit_cast(short8, bi);
#pragma unroll
        for (int t = 0; t < MFRAG; ++t) {
            short8 a = *reinterpret_cast<const short8*>(ap + (size_t)t * mstride);
            acc[t] = __builtin_amdgcn_mfma_f32_32x32x16_bf16(a, bf, acc[t], 0, 0, 0);
        }
        bp += 16; ap += 16;
    }

    // C/D layout (verified m74/m101): col(n)=lane&31, row(m)=(r&3)+8*(r>>2)+4*(lane>>5)
#pragma unroll
    for (int t = 0; t < MFRAG; ++t)
#pragma unroll
        for (int r = 0; r < 16; ++r) {
            int m = m0 + t * 32 + (r & 3) + 8 * (r >> 2) + 4 * (lane >> 5);
            size_t idx = (size_t)ks * MTOK * (size_t)N + (size_t)m * N + n;
            if (OBF16) ((unsigned short*)part)[idx] = f2bf_rne(acc[t][r]);
            else       ((float*)part)[idx] = acc[t][r];
        }
}

// ---------------- combine KS1 bf16 partials, scale, SwiGLU -> h bf16 ----------------
__global__ void swiglu_k(const unsigned short* __restrict__ y,  // [KS1][MTOK][NMERG] bf16
                         const float* __restrict__ s1, const float* __restrict__ s3,
                         unsigned short* __restrict__ h)        // [MTOK][INTER] bf16
{
    int i = blockIdx.x * 256 + threadIdx.x;      // over MTOK*INTER/4
    int m = i / (INTER / 4);
    int j = (i % (INTER / 4)) * 4;
    size_t base = (size_t)m * NMERG + j;
    float up[4] = {0.f, 0.f, 0.f, 0.f}, gt[4] = {0.f, 0.f, 0.f, 0.f};
#pragma unroll
    for (int s = 0; s < KS1; ++s) {
        size_t o = (size_t)s * MTOK * NMERG + base;
        ushort4 a = *(const ushort4*)(y + o);
        ushort4 g = *(const ushort4*)(y + o + INTER);
        up[0] += bf2f(a.x); up[1] += bf2f(a.y); up[2] += bf2f(a.z); up[3] += bf2f(a.w);
        gt[0] += bf2f(g.x); gt[1] += bf2f(g.y); gt[2] += bf2f(g.z); gt[3] += bf2f(g.w);
    }
    float4 c1 = *(const float4*)(s1 + j);
    float4 c3 = *(const float4*)(s3 + j);
    ushort4 o;
    { float u = up[0] * c1.x, g = gt[0] * c3.x; o.x = f2bf_rne(g * u / (1.f + __expf(-u))); }
    { float u = up[1] * c1.y, g = gt[1] * c3.y; o.y = f2bf_rne(g * u / (1.f + __expf(-u))); }
    { float u = up[2] * c1.z, g = gt[2] * c3.z; o.z = f2bf_rne(g * u / (1.f + __expf(-u))); }
    { float u = up[3] * c1.w, g = gt[3] * c3.w; o.w = f2bf_rne(g * u / (1.f + __expf(-u))); }
    *(ushort4*)(h + (size_t)m * INTER + j) = o;
}

// ---------------- reduce KS2 fp32 partials, scale by w2_s ----------------
__global__ void reduce_k(const float* __restrict__ p,   // [KS2][MTOK][HIDDEN]
                         const float* __restrict__ s2, float* __restrict__ out)
{
    int i = (blockIdx.x * 256 + threadIdx.x) * 4;
    float4 acc = *(const float4*)(p + i);
#pragma unroll
    for (int s = 1; s < KS2; ++s) {
        float4 v = *(const float4*)(p + (size_t)s * MTOK * HIDDEN + i);
        acc.x += v.x; acc.y += v.y; acc.z += v.z; acc.w += v.w;
    }
    int ncol = i & (HIDDEN - 1);
    float4 sc = *(const float4*)(s2 + ncol);
    acc.x *= sc.x; acc.y *= sc.y; acc.z *= sc.z; acc.w *= sc.w;
    *(float4*)(out + i) = acc;
}

extern "C" void kernel_launch(void* const* d_in, const int* in_sizes, int n_in,
                              void* d_out, int out_size, void* d_ws, size_t ws_size,
                              hipStream_t stream) {
    const float* x   = (const float*)d_in[0];
    const float* w1q = (const float*)d_in[1];
    const float* w1s = (const float*)d_in[2];
    const float* w3q = (const float*)d_in[3];
    const float* w3s = (const float*)d_in[4];
    const float* w2q = (const float*)d_in[5];
    const float* w2s = (const float*)d_in[6];
    float* out = (float*)d_out;

    char* ws = (char*)d_ws;
    unsigned short* xb = (unsigned short*)ws;                    // 1 MB   : x bf16 [128][4096]
    unsigned short* h  = (unsigned short*)(ws + (1u << 20));     // 2.75 MB: h bf16 [128][11008]
    void* part         = (void*)(ws + (4u << 20));               // 45 MB  : partials (reused)

    // 1) x -> bf16
    cvt_x_k<<<MTOK * HIDDEN / 4 / 256, 256, 0, stream>>>(x, xb);
    // 2) up/gate partials: merged N = [w1;w3], K-split 8, bf16 partials (45 MB)
    gemm_part_k<4, 0, true><<<dim3(NMERG / 64, KS1), 128, 0, stream>>>(
        xb, w1q, w3q, INTER, part, HIDDEN, NMERG, HIDDEN / KS1);
    // 3) SwiGLU -> h bf16
    swiglu_k<<<MTOK * INTER / 4 / 256, 256, 0, stream>>>(
        (const unsigned short*)part, w1s, w3s, h);
    // 4) out partials: h @ w2^T, K-split 16, m-split 2, fp32 partials (33.5 MB)
    gemm_part_k<2, 1, false><<<dim3(HIDDEN / 64 * 2, KS2), 128, 0, stream>>>(
        h, w2q, w2q, 1 << 30, part, INTER, HIDDEN, INTER / KS2);
    // 5) reduce + scale
    reduce_k<<<MTOK * HIDDEN / 4 / 256, 256, 0, stream>>>(
        (const float*)part, w2s, out);
}

// Round 3
// 540.595 us; speedup vs baseline: 1.3290x; 1.3290x over previous
//
#include <hip/hip_runtime.h>

#define HIDDEN 4096
#define INTER  11008
#define MTOK   128          // B*S
#define NMERG  (2*INTER)    // 22016
#define KS1    4            // stage-1 K-split (bf16 partials, 22.5 MB)
#define KS2    16           // stage-2 K-split (fp32 partials, 33.5 MB)

typedef short          short8  __attribute__((ext_vector_type(8)));
typedef unsigned short ushort8 __attribute__((ext_vector_type(8)));
typedef float          f32x16  __attribute__((ext_vector_type(16)));
#define AS1 __attribute__((address_space(1)))
#define AS3 __attribute__((address_space(3)))

static __device__ __forceinline__ unsigned short f2bf_rne(float f) {
    unsigned u = __builtin_bit_cast(unsigned, f);
    u += 0x7FFFu + ((u >> 16) & 1u);
    return (unsigned short)(u >> 16);
}
static __device__ __forceinline__ float bf2f(unsigned short b) {
    unsigned u = (unsigned)b << 16;
    return __builtin_bit_cast(float, u);
}
// pack two fp32 -> bf16x2 by truncation (exact for integer-valued weights)
static __device__ __forceinline__ int pk2(float lo, float hi) {
    return (int)__builtin_amdgcn_perm(__builtin_bit_cast(unsigned, hi),
                                      __builtin_bit_cast(unsigned, lo),
                                      0x07060302u);
}

// ---- x fp32 -> bf16 in MFMA A-fragment order ----
// A2[((kstep*4+ms)*64+lane)*8 + j] = bf16(x[m][k]), m=ms*32+(lane&31), k=kstep*16+(lane>>5)*8+j
__global__ void cvt_x_k(const float* __restrict__ x, unsigned short* __restrict__ A2) {
    int f = blockIdx.x * 256 + threadIdx.x;
    int lane = f & 63, w = f >> 6;
    int kstep = w >> 2, ms = w & 3;
    int m = ms * 32 + (lane & 31);
    int k = kstep * 16 + (lane >> 5) * 8;
    const float* src = x + (size_t)m * HIDDEN + k;
    float4 v0 = *(const float4*)(src);
    float4 v1 = *(const float4*)(src + 4);
    ushort8 o;
    o[0] = f2bf_rne(v0.x); o[1] = f2bf_rne(v0.y); o[2] = f2bf_rne(v0.z); o[3] = f2bf_rne(v0.w);
    o[4] = f2bf_rne(v1.x); o[5] = f2bf_rne(v1.y); o[6] = f2bf_rne(v1.z); o[7] = f2bf_rne(v1.w);
    *(ushort8*)(A2 + (size_t)f * 8) = o;
}

// ---- LDS-staged dequant GEMM partial ----
// part[ks][m][n] = sum_{k chunk} A[m][k]*B[n][k].  BN=128 rows/block, BK=64 fp32.
// Weights staged global->LDS (32KB fp32) with XOR-16 atom swizzle; A2 fragment-ordered global.
template<bool OBF16>
__global__ __launch_bounds__(256) void gemm_k(
    const unsigned short* __restrict__ A2,
    const float* __restrict__ B0, const float* __restrict__ B1, int nhalf,
    void* __restrict__ part, int K, int N, int totTiles, int ksplit)
{
    __shared__ __align__(16) float lds[8192];   // 128 rows x 16 atoms(16B) fp32
    const int lane = threadIdx.x & 63;
    const int ws   = threadIdx.x >> 6;
    const int n0   = blockIdx.x * 128;
    const int ks   = blockIdx.y;
    const int tbeg = (ks * totTiles) / ksplit;
    const int tend = ((ks + 1) * totTiles) / ksplit;

    // per-lane global staging bases (8 issues/wave, 1KB each)
    const char* gbase[8];
#pragma unroll
    for (int i = 0; i < 8; ++i) {
        int s = ws * 512 + i * 64 + lane;          // LDS atom slot
        int n = s >> 4;                            // tile-local row
        int a = (s & 15) ^ (n & 15);               // swizzled source atom
        const float* rowp = (n0 + n < nhalf) ? (B0 + (size_t)(n0 + n) * K)
                                             : (B1 + (size_t)(n0 + n - nhalf) * K);
        gbase[i] = (const char*)rowp + a * 16;
    }

    f32x16 acc[4];
#pragma unroll
    for (int t = 0; t < 4; ++t)
#pragma unroll
        for (int r = 0; r < 16; ++r) acc[t][r] = 0.f;

    const int nl = ws * 32 + (lane & 31);          // tile-local weight row this lane consumes

    for (int t = tbeg; t < tend; ++t) {
        const size_t koff = (size_t)t * 64 * 4;    // byte offset along row
#pragma unroll
        for (int i = 0; i < 8; ++i) {
            __builtin_amdgcn_global_load_lds(
                (const AS1 unsigned*)(gbase[i] + koff),
                (AS3 unsigned*)((char*)lds + ws * 8192 + i * 1024), 16, 0, 0);
        }
        __syncthreads();

#pragma unroll
        for (int step = 0; step < 4; ++step) {
            int a0 = step * 4 + ((lane >> 5) << 1);
            int p0 = nl * 16 + (a0 ^ (nl & 15));
            int p1 = nl * 16 + ((a0 + 1) ^ (nl & 15));
            float4 v0 = *(const float4*)((const char*)lds + p0 * 16);
            float4 v1 = *(const float4*)((const char*)lds + p1 * 16);
            int4 bi;
            bi.x = pk2(v0.x, v0.y); bi.y = pk2(v0.z, v0.w);
            bi.z = pk2(v1.x, v1.y); bi.w = pk2(v1.z, v1.w);
            short8 bf = __builtin_bit_cast(short8, bi);
            int kg = t * 4 + step;                 // global 16-k step index
#pragma unroll
            for (int ms = 0; ms < 4; ++ms) {
                short8 af = *(const short8*)(A2 + ((size_t)(kg * 4 + ms) * 64 + lane) * 8);
                acc[ms] = __builtin_amdgcn_mfma_f32_32x32x16_bf16(af, bf, acc[ms], 0, 0, 0);
            }
        }
        __syncthreads();
    }

    // C/D layout: col=lane&31, row=(r&3)+8*(r>>2)+4*(lane>>5)
    const int n = n0 + ws * 32 + (lane & 31);
#pragma unroll
    for (int ms = 0; ms < 4; ++ms)
#pragma unroll
        for (int r = 0; r < 16; ++r) {
            int m = ms * 32 + (r & 3) + 8 * (r >> 2) + 4 * (lane >> 5);
            size_t idx = ((size_t)ks * MTOK + m) * (size_t)N + n;
            if (OBF16) ((unsigned short*)part)[idx] = f2bf_rne(acc[ms][r]);
            else       ((float*)part)[idx] = acc[ms][r];
        }
}

// ---- combine KS1 bf16 partials, scale, SwiGLU -> h in fragment order ----
__global__ void swiglu_k(const unsigned short* __restrict__ p1,  // [KS1][MTOK][NMERG] bf16
                         const float* __restrict__ s1, const float* __restrict__ s3,
                         unsigned short* __restrict__ h2)        // fragment-ordered, K=INTER
{
    int f = blockIdx.x * 256 + threadIdx.x;
    int lane = f & 63, w = f >> 6;
    int kstep = w >> 2, ms = w & 3;
    int m = ms * 32 + (lane & 31);
    int j = kstep * 16 + (lane >> 5) * 8;
    float up[8], gt[8];
#pragma unroll
    for (int e = 0; e < 8; ++e) { up[e] = 0.f; gt[e] = 0.f; }
#pragma unroll
    for (int ks = 0; ks < KS1; ++ks) {
        const unsigned short* pu = p1 + ((size_t)ks * MTOK + m) * NMERG + j;
        ushort8 u = *(const ushort8*)(pu);
        ushort8 g = *(const ushort8*)(pu + INTER);
#pragma unroll
        for (int e = 0; e < 8; ++e) { up[e] += bf2f(u[e]); gt[e] += bf2f(g[e]); }
    }
    float4 c1a = *(const float4*)(s1 + j), c1b = *(const float4*)(s1 + j + 4);
    float4 c3a = *(const float4*)(s3 + j), c3b = *(const float4*)(s3 + j + 4);
    float c1[8] = {c1a.x, c1a.y, c1a.z, c1a.w, c1b.x, c1b.y, c1b.z, c1b.w};
    float c3[8] = {c3a.x, c3a.y, c3a.z, c3a.w, c3b.x, c3b.y, c3b.z, c3b.w};
    ushort8 o;
#pragma unroll
    for (int e = 0; e < 8; ++e) {
        float u = up[e] * c1[e], g = gt[e] * c3[e];
        o[e] = f2bf_rne(g * u / (1.f + __expf(-u)));
    }
    *(ushort8*)(h2 + (size_t)f * 8) = o;
}

// ---- reduce KS2 fp32 partials, scale by w2_s ----
__global__ void reduce_k(const float* __restrict__ p, const float* __restrict__ s2,
                         float* __restrict__ out)
{
    int i = (blockIdx.x * 256 + threadIdx.x) * 4;
    float4 acc = *(const float4*)(p + i);
#pragma unroll
    for (int s = 1; s < KS2; ++s) {
        float4 v = *(const float4*)(p + (size_t)s * MTOK * HIDDEN + i);
        acc.x += v.x; acc.y += v.y; acc.z += v.z; acc.w += v.w;
    }
    int ncol = i & (HIDDEN - 1);
    float4 sc = *(const float4*)(s2 + ncol);
    acc.x *= sc.x; acc.y *= sc.y; acc.z *= sc.z; acc.w *= sc.w;
    *(float4*)(out + i) = acc;
}

extern "C" void kernel_launch(void* const* d_in, const int* in_sizes, int n_in,
                              void* d_out, int out_size, void* d_ws, size_t ws_size,
                              hipStream_t stream) {
    const float* x   = (const float*)d_in[0];
    const float* w1q = (const float*)d_in[1];
    const float* w1s = (const float*)d_in[2];
    const float* w3q = (const float*)d_in[3];
    const float* w3s = (const float*)d_in[4];
    const float* w2q = (const float*)d_in[5];
    const float* w2s = (const float*)d_in[6];
    float* out = (float*)d_out;

    char* ws = (char*)d_ws;
    unsigned short* xb2 = (unsigned short*)ws;                 // 1 MB   fragment-ordered x
    unsigned short* h2  = (unsigned short*)(ws + (1u << 20));  // 2.75 MB fragment-ordered h
    void* part          = (void*)(ws + (4u << 20));            // max 33.5 MB partials

    // 1) x -> bf16 fragments
    cvt_x_k<<<MTOK * HIDDEN / 8 / 256, 256, 0, stream>>>(x, xb2);
    // 2) up/gate: merged [w1;w3], N=22016, K=4096, 64 tiles, K-split 4, bf16 partials
    gemm_k<true><<<dim3(NMERG / 128, KS1), 256, 0, stream>>>(
        xb2, w1q, w3q, INTER, part, HIDDEN, NMERG, HIDDEN / 64, KS1);
    // 3) SwiGLU -> h fragments
    swiglu_k<<<MTOK * INTER / 8 / 256, 256, 0, stream>>>(
        (const unsigned short*)part, w1s, w3s, h2);
    // 4) out: w2, N=4096, K=11008, 172 tiles, K-split 16, fp32 partials
    gemm_k<false><<<dim3(HIDDEN / 128, KS2), 256, 0, stream>>>(
        h2, w2q, w2q, 1 << 30, part, INTER, HIDDEN, INTER / 64, KS2);
    // 5) reduce + scale
    reduce_k<<<MTOK * HIDDEN / 4 / 256, 256, 0, stream>>>(
        (const float*)part, w2s, out);
}